// Round 4
// baseline (851.405 us; speedup 1.0000x reference)
//
#include <hip/hip_runtime.h>
#include <cstddef>

// Grouped GRU: B=32, C=512, T=2000, G=8, I=64, H=64
// One block per (b,g): 256 blocks == 256 CUs.
// 256 threads = 4 waves (1 per SIMD). Thread (j, sub): j = tid>>2 (element),
// sub = tid&3 (16-wide slice of the 64-deep dots). All three gates of element
// j live in one quad -> 2-level DPP quad reduce, ONE barrier per step.
// Round-4 changes vs round 3:
//  * raw `s_waitcnt lgkmcnt(0); s_barrier` instead of __syncthreads() --
//    the per-step global out-store / x-prefetch stay in flight across the
//    barrier (no vmcnt(0) drain: that was ~half the step time).
//  * weight pin moved INSIDE the T-loop (defeats AGPR shuttling/remat).
//  * fp32 h carry lives in a register on sub==0 lanes (no h_f LDS plane).

typedef _Float16 h2 __attribute__((ext_vector_type(2)));

constexpr int B_ = 32;
constexpr int C_ = 512;
constexpr int T_ = 2000;
constexpr int G_ = 8;
constexpr int I_ = 64;
constexpr int H_ = 64;
constexpr int K3_ = 3 * H_;  // 192

// LDS-write visibility across waves, WITHOUT draining vmcnt (global ops
// in flight stay in flight). Single asm so nothing reorders between the
// waitcnt and the barrier.
#define BARRIER_LGKM() asm volatile("s_waitcnt lgkmcnt(0)\n\ts_barrier" ::: "memory")

template <int CTRL>
__device__ __forceinline__ float dpp_xadd(float v) {
    int p = __builtin_amdgcn_update_dpp(0, __float_as_int(v), CTRL, 0xF, 0xF, true);
    return v + __int_as_float(p);
}
// Sum across the 4 lanes of a quad (sub 0..3); every lane gets the sum.
__device__ __forceinline__ float reduce4(float v) {
    v = dpp_xadd<0xB1>(v);   // quad_perm [1,0,3,2] : xor 1
    v = dpp_xadd<0x4E>(v);   // quad_perm [2,3,0,1] : xor 2
    return v;
}

__device__ __forceinline__ float sigmoid_f(float x) {
    float e = __expf(-x);
    return __builtin_amdgcn_rcpf(1.0f + e);
}
__device__ __forceinline__ float tanh_f(float x) {
    // tanh(x) = 1 - 2/(exp(2x)+1); exp overflow -> inf -> rcp -> 0 -> 1 (no NaN)
    float e = __expf(2.0f * x);
    return 1.0f - 2.0f * __builtin_amdgcn_rcpf(e + 1.0f);
}

__device__ __forceinline__ float fdot2_(h2 a, h2 b, float c) {
#if __has_builtin(__builtin_amdgcn_fdot2)
    return __builtin_amdgcn_fdot2(a, b, c, false);
#else
    return fmaf((float)a[0], (float)b[0], fmaf((float)a[1], (float)b[1], c));
#endif
}

// Load 16 halves (32B, 16B-aligned) from LDS as two b128 reads -> 8 packed h2.
__device__ __forceinline__ void ld_h2x8(const _Float16* p, h2* d) {
    const float4* p4 = reinterpret_cast<const float4*>(p);
    float4 a = p4[0], b = p4[1];
    d[0] = __builtin_bit_cast(h2, a.x); d[1] = __builtin_bit_cast(h2, a.y);
    d[2] = __builtin_bit_cast(h2, a.z); d[3] = __builtin_bit_cast(h2, a.w);
    d[4] = __builtin_bit_cast(h2, b.x); d[5] = __builtin_bit_cast(h2, b.y);
    d[6] = __builtin_bit_cast(h2, b.z); d[7] = __builtin_bit_cast(h2, b.w);
}

__global__ __launch_bounds__(256, 1)
void gru_scan_kernel(const float* __restrict__ x,
                     const float* __restrict__ h0,
                     const float* __restrict__ w_ih,
                     const float* __restrict__ w_hh,
                     const float* __restrict__ b_ih,
                     const float* __restrict__ b_hh,
                     float* __restrict__ out)
{
    const int bid = blockIdx.x;        // 0..255
    const int g = bid & (G_ - 1);
    const int b = bid >> 3;
    const int tid = threadIdx.x;       // 0..255
    const int j = tid >> 2;            // element 0..63
    const int sub = tid & 3;           // dot slice 0..3 (16 inputs each)

    __shared__ __align__(16) _Float16 h_h[2][H_];   // fp16 h (dot input)
    __shared__ __align__(16) _Float16 xbuf[2][I_];  // fp16 x slices

    // ---- Weight slices -> packed fp16 in registers.
    // Rows {j, j+64, j+128}, cols [16*sub, 16*sub+16).
    h2 Wir[8], Wiz[8], Win[8], Whr[8], Whz[8], Whn[8];
    {
        const size_t rb = (size_t)g * K3_ + j;
        auto loadrow = [&](const float* p, h2* w) {
            const float4* p4 = reinterpret_cast<const float4*>(p);
            #pragma unroll
            for (int q = 0; q < 4; ++q) {
                float4 a = p4[q];
                w[2*q+0] = h2{(_Float16)a.x, (_Float16)a.y};
                w[2*q+1] = h2{(_Float16)a.z, (_Float16)a.w};
            }
        };
        loadrow(w_ih + (rb           ) * I_ + sub * 16, Wir);
        loadrow(w_ih + (rb +     H_  ) * I_ + sub * 16, Wiz);
        loadrow(w_ih + (rb + 2 * H_  ) * I_ + sub * 16, Win);
        loadrow(w_hh + (rb           ) * H_ + sub * 16, Whr);
        loadrow(w_hh + (rb +     H_  ) * H_ + sub * 16, Whz);
        loadrow(w_hh + (rb + 2 * H_  ) * H_ + sub * 16, Whn);
    }

    const float brc = b_ih[g * K3_ + j]           + b_hh[g * K3_ + j];
    const float bzc = b_ih[g * K3_ + H_ + j]      + b_hh[g * K3_ + H_ + j];
    const float bin = b_ih[g * K3_ + 2 * H_ + j];
    const float bhn = b_hh[g * K3_ + 2 * H_ + j];

    const float* xbase = x + ((size_t)b * C_ + (size_t)g * I_) * T_;  // [i*T + t]
    float* outbase = out + ((size_t)b * (G_ * H_) + (size_t)g * H_) * T_;

    // ---- Init h(0), x(0), x(1); fp32 h carry lives in sub==0 registers.
    float h_reg = 0.0f;
    {
        float hv0 = h0[((size_t)g * B_ + b) * H_ + j];
        if (sub == 0) h_reg = hv0;
    }
    if (tid < H_) {
        h_h[0][tid] = (_Float16)h0[((size_t)g * B_ + b) * H_ + tid];
        xbuf[0][tid] = (_Float16)xbase[(size_t)tid * T_];
        xbuf[1][tid] = (_Float16)xbase[(size_t)tid * T_ + 1];
    }
    __syncthreads();

    // xp partials for step 0 (from xbuf[0])
    float xr_s = 0.f, xz_s = 0.f, xn_s = 0.f;
    {
        h2 xv[8]; ld_h2x8(&xbuf[0][sub * 16], xv);
        #pragma unroll
        for (int i = 0; i < 8; ++i) {
            xr_s = fdot2_(Wir[i], xv[i], xr_s);
            xz_s = fdot2_(Wiz[i], xv[i], xz_s);
            xn_s = fdot2_(Win[i], xv[i], xn_s);
        }
    }
    __syncthreads();  // xbuf[0] consumed; safe to overwrite at t=0

    for (int t = 0; t < T_; ++t) {
        const int cur = t & 1, nxt = cur ^ 1;

        // Pin weights in arch VGPRs EVERY iteration: the allocator can
        // neither rematerialize the loads nor shuttle through AGPRs.
        #pragma unroll
        for (int i = 0; i < 8; ++i) {
            asm volatile("" : "+v"(Wir[i]), "+v"(Wiz[i]), "+v"(Win[i]),
                              "+v"(Whr[i]), "+v"(Whz[i]), "+v"(Whn[i]));
        }

        // h-dot partials for step t (critical path)
        h2 hv[8]; ld_h2x8(&h_h[cur][sub * 16], hv);
        float hr = 0.f, hz = 0.f, hn = 0.f;
        #pragma unroll
        for (int i = 0; i < 8; ++i) {
            hr = fdot2_(Whr[i], hv[i], hr);
            hz = fdot2_(Whz[i], hv[i], hz);
            hn = fdot2_(Whn[i], hv[i], hn);
        }

        // xp partials for step t+1 (independent filler work)
        h2 xv[8]; ld_h2x8(&xbuf[nxt][sub * 16], xv);
        float xr2 = 0.f, xz2 = 0.f, xn2 = 0.f;
        #pragma unroll
        for (int i = 0; i < 8; ++i) {
            xr2 = fdot2_(Wir[i], xv[i], xr2);
            xz2 = fdot2_(Wiz[i], xv[i], xz2);
            xn2 = fdot2_(Win[i], xv[i], xn2);
        }

        // Prefetch global x(t+2) -- stays in flight across the raw barrier.
        float xg = 0.f;
        if (tid < I_ && t + 2 < T_) xg = xbase[(size_t)tid * T_ + (t + 2)];

        // Quad reduces (2-level DPP)
        const float pre_r  = reduce4(xr_s + hr) + brc;
        const float pre_z  = reduce4(xz_s + hz) + bzc;
        const float xn_sum = reduce4(xn_s) + bin;
        const float hn_sum = reduce4(hn) + bhn;

        const float r = sigmoid_f(pre_r);
        const float z = sigmoid_f(pre_z);
        const float n = tanh_f(xn_sum + r * hn_sum);
        const float hnew = (1.0f - z) * n + z * h_reg;  // h_reg valid on sub==0

        if (sub == 0) {
            h_h[nxt][j] = (_Float16)hnew;
            outbase[(size_t)j * T_ + t] = hnew;
            h_reg = hnew;
        }
        if (tid < I_) xbuf[cur][tid] = (_Float16)xg;

        xr_s = xr2; xz_s = xz2; xn_s = xn2;

        // LDS visibility only; global stores/loads NOT drained.
        BARRIER_LGKM();
    }
}

extern "C" void kernel_launch(void* const* d_in, const int* in_sizes, int n_in,
                              void* d_out, int out_size, void* d_ws, size_t ws_size,
                              hipStream_t stream)
{
    const float* x    = (const float*)d_in[0];
    const float* h0   = (const float*)d_in[1];
    const float* w_ih = (const float*)d_in[2];
    const float* w_hh = (const float*)d_in[3];
    const float* b_ih = (const float*)d_in[4];
    const float* b_hh = (const float*)d_in[5];
    float* out = (float*)d_out;

    dim3 grid(B_ * G_);   // 256 blocks, one per (b,g)
    dim3 block(256);      // 4 waves, 1 per SIMD
    gru_scan_kernel<<<grid, block, 0, stream>>>(x, h0, w_ih, w_hh, b_ih, b_hh, out);
}

// Round 5
// 827.546 us; speedup vs baseline: 1.0288x; 1.0288x over previous
//
#include <hip/hip_runtime.h>
#include <cstddef>

// Grouped GRU: B=32, C=512, T=2000, G=8, I=64, H=64
// One block per (b,g): 256 blocks == 256 CUs.
// 256 threads = 4 waves (1 per SIMD). Thread (j, sub): j = tid>>2 (element),
// sub = tid&3 (16-wide slice of the 64-deep dots). All three gates of element
// j live in one quad -> 2-level DPP quad reduce, ONE barrier per step.
// Round-5: EXACTLY round-3 except the in-loop __syncthreads() is replaced by
// `s_waitcnt lgkmcnt(0); s_barrier` (LDS visibility only). The per-step
// out-store and x-prefetch are NOT drained at the barrier (they were the
// suspected ~350 cyc/step stall). Weight pin stays OUTSIDE the loop (the
// round-4 in-loop pin was a scheduling fence and regressed).

typedef _Float16 h2 __attribute__((ext_vector_type(2)));

constexpr int B_ = 32;
constexpr int C_ = 512;
constexpr int T_ = 2000;
constexpr int G_ = 8;
constexpr int I_ = 64;
constexpr int H_ = 64;
constexpr int K3_ = 3 * H_;  // 192

// LDS-write visibility across waves WITHOUT draining vmcnt: in-flight global
// stores/loads stay in flight across the barrier. Cross-wave traffic in the
// loop is LDS-only, so this is sufficient for correctness.
#define BARRIER_LGKM() asm volatile("s_waitcnt lgkmcnt(0)\n\ts_barrier" ::: "memory")

template <int CTRL>
__device__ __forceinline__ float dpp_xadd(float v) {
    int p = __builtin_amdgcn_update_dpp(0, __float_as_int(v), CTRL, 0xF, 0xF, true);
    return v + __int_as_float(p);
}
// Sum across the 4 lanes of a quad (sub 0..3); every lane gets the sum.
__device__ __forceinline__ float reduce4(float v) {
    v = dpp_xadd<0xB1>(v);   // quad_perm [1,0,3,2] : xor 1
    v = dpp_xadd<0x4E>(v);   // quad_perm [2,3,0,1] : xor 2
    return v;
}

__device__ __forceinline__ float sigmoid_f(float x) {
    float e = __expf(-x);
    return __builtin_amdgcn_rcpf(1.0f + e);
}
__device__ __forceinline__ float tanh_f(float x) {
    // tanh(x) = 1 - 2/(exp(2x)+1); exp overflow -> inf -> rcp -> 0 -> 1 (no NaN)
    float e = __expf(2.0f * x);
    return 1.0f - 2.0f * __builtin_amdgcn_rcpf(e + 1.0f);
}

__device__ __forceinline__ float fdot2_(h2 a, h2 b, float c) {
#if __has_builtin(__builtin_amdgcn_fdot2)
    return __builtin_amdgcn_fdot2(a, b, c, false);
#else
    return fmaf((float)a[0], (float)b[0], fmaf((float)a[1], (float)b[1], c));
#endif
}

// Load 16 halves (32B, 16B-aligned) from LDS as two b128 reads -> 8 packed h2.
__device__ __forceinline__ void ld_h2x8(const _Float16* p, h2* d) {
    const float4* p4 = reinterpret_cast<const float4*>(p);
    float4 a = p4[0], b = p4[1];
    d[0] = __builtin_bit_cast(h2, a.x); d[1] = __builtin_bit_cast(h2, a.y);
    d[2] = __builtin_bit_cast(h2, a.z); d[3] = __builtin_bit_cast(h2, a.w);
    d[4] = __builtin_bit_cast(h2, b.x); d[5] = __builtin_bit_cast(h2, b.y);
    d[6] = __builtin_bit_cast(h2, b.z); d[7] = __builtin_bit_cast(h2, b.w);
}

__global__ __launch_bounds__(256, 1)
void gru_scan_kernel(const float* __restrict__ x,
                     const float* __restrict__ h0,
                     const float* __restrict__ w_ih,
                     const float* __restrict__ w_hh,
                     const float* __restrict__ b_ih,
                     const float* __restrict__ b_hh,
                     float* __restrict__ out)
{
    const int bid = blockIdx.x;        // 0..255
    const int g = bid & (G_ - 1);
    const int b = bid >> 3;
    const int tid = threadIdx.x;       // 0..255
    const int j = tid >> 2;            // element 0..63
    const int sub = tid & 3;           // dot slice 0..3 (16 inputs each)

    __shared__ __align__(16) _Float16 h_h[2][H_];   // fp16 h (dot input)
    __shared__ float h_f[2][H_];                    // fp32 h (carry)
    __shared__ __align__(16) _Float16 xbuf[2][I_];  // fp16 x slices

    // ---- Weight slices -> packed fp16 in registers.
    // Rows {j, j+64, j+128}, cols [16*sub, 16*sub+16).
    h2 Wir[8], Wiz[8], Win[8], Whr[8], Whz[8], Whn[8];
    {
        const size_t rb = (size_t)g * K3_ + j;
        auto loadrow = [&](const float* p, h2* w) {
            const float4* p4 = reinterpret_cast<const float4*>(p);
            #pragma unroll
            for (int q = 0; q < 4; ++q) {
                float4 a = p4[q];
                w[2*q+0] = h2{(_Float16)a.x, (_Float16)a.y};
                w[2*q+1] = h2{(_Float16)a.z, (_Float16)a.w};
            }
        };
        loadrow(w_ih + (rb           ) * I_ + sub * 16, Wir);
        loadrow(w_ih + (rb +     H_  ) * I_ + sub * 16, Wiz);
        loadrow(w_ih + (rb + 2 * H_  ) * I_ + sub * 16, Win);
        loadrow(w_hh + (rb           ) * H_ + sub * 16, Whr);
        loadrow(w_hh + (rb +     H_  ) * H_ + sub * 16, Whz);
        loadrow(w_hh + (rb + 2 * H_  ) * H_ + sub * 16, Whn);
    }
    // Pin weights in VGPRs ONCE (outside the loop): the value is no longer
    // provably == memory, so the loads cannot be sunk into the T-loop.
    #pragma unroll
    for (int i = 0; i < 8; ++i) {
        asm volatile("" : "+v"(Wir[i]), "+v"(Wiz[i]), "+v"(Win[i]),
                          "+v"(Whr[i]), "+v"(Whz[i]), "+v"(Whn[i]));
    }

    const float brc = b_ih[g * K3_ + j]           + b_hh[g * K3_ + j];
    const float bzc = b_ih[g * K3_ + H_ + j]      + b_hh[g * K3_ + H_ + j];
    const float bin = b_ih[g * K3_ + 2 * H_ + j];
    const float bhn = b_hh[g * K3_ + 2 * H_ + j];

    const float* xbase = x + ((size_t)b * C_ + (size_t)g * I_) * T_;  // [i*T + t]
    float* outbase = out + ((size_t)b * (G_ * H_) + (size_t)g * H_) * T_;

    // ---- Init h(0), x(0), x(1)
    if (tid < H_) {
        float hv = h0[((size_t)g * B_ + b) * H_ + tid];
        h_f[0][tid] = hv;
        h_h[0][tid] = (_Float16)hv;
        xbuf[0][tid] = (_Float16)xbase[(size_t)tid * T_];
        xbuf[1][tid] = (_Float16)xbase[(size_t)tid * T_ + 1];
    }
    __syncthreads();

    // xp partials for step 0 (from xbuf[0])
    float xr_s = 0.f, xz_s = 0.f, xn_s = 0.f;
    {
        h2 xv[8]; ld_h2x8(&xbuf[0][sub * 16], xv);
        #pragma unroll
        for (int i = 0; i < 8; ++i) {
            xr_s = fdot2_(Wir[i], xv[i], xr_s);
            xz_s = fdot2_(Wiz[i], xv[i], xz_s);
            xn_s = fdot2_(Win[i], xv[i], xn_s);
        }
    }
    __syncthreads();  // xbuf[0] consumed; safe for wave0 to overwrite at t=0

    for (int t = 0; t < T_; ++t) {
        const int cur = t & 1, nxt = cur ^ 1;

        // h-dot partials for step t (critical path)
        h2 hv[8]; ld_h2x8(&h_h[cur][sub * 16], hv);
        float hr = 0.f, hz = 0.f, hn = 0.f;
        #pragma unroll
        for (int i = 0; i < 8; ++i) {
            hr = fdot2_(Whr[i], hv[i], hr);
            hz = fdot2_(Whz[i], hv[i], hz);
            hn = fdot2_(Whn[i], hv[i], hn);
        }
        const float h_old = h_f[cur][j];

        // xp partials for step t+1 (independent filler work)
        h2 xv[8]; ld_h2x8(&xbuf[nxt][sub * 16], xv);
        float xr2 = 0.f, xz2 = 0.f, xn2 = 0.f;
        #pragma unroll
        for (int i = 0; i < 8; ++i) {
            xr2 = fdot2_(Wir[i], xv[i], xr2);
            xz2 = fdot2_(Wiz[i], xv[i], xz2);
            xn2 = fdot2_(Win[i], xv[i], xn2);
        }

        // Prefetch global x(t+2)
        float xg = 0.f;
        if (tid < I_ && t + 2 < T_) xg = xbase[(size_t)tid * T_ + (t + 2)];

        // Quad reduces (2-level DPP)
        const float pre_r  = reduce4(xr_s + hr) + brc;
        const float pre_z  = reduce4(xz_s + hz) + bzc;
        const float xn_sum = reduce4(xn_s) + bin;
        const float hn_sum = reduce4(hn) + bhn;

        const float r = sigmoid_f(pre_r);
        const float z = sigmoid_f(pre_z);
        const float n = tanh_f(xn_sum + r * hn_sum);
        const float hnew = (1.0f - z) * n + z * h_old;

        if (sub == 0) {
            h_f[nxt][j] = hnew;
            h_h[nxt][j] = (_Float16)hnew;
            outbase[(size_t)j * T_ + t] = hnew;
        }
        if (tid < I_) xbuf[cur][tid] = (_Float16)xg;

        xr_s = xr2; xz_s = xz2; xn_s = xn2;

        // LDS visibility only; out-store and x-prefetch stay in flight.
        BARRIER_LGKM();
    }
}

extern "C" void kernel_launch(void* const* d_in, const int* in_sizes, int n_in,
                              void* d_out, int out_size, void* d_ws, size_t ws_size,
                              hipStream_t stream)
{
    const float* x    = (const float*)d_in[0];
    const float* h0   = (const float*)d_in[1];
    const float* w_ih = (const float*)d_in[2];
    const float* w_hh = (const float*)d_in[3];
    const float* b_ih = (const float*)d_in[4];
    const float* b_hh = (const float*)d_in[5];
    float* out = (float*)d_out;

    dim3 grid(B_ * G_);   // 256 blocks, one per (b,g)
    dim3 block(256);      // 4 waves, 1 per SIMD
    gru_scan_kernel<<<grid, block, 0, stream>>>(x, h0, w_ih, w_hh, b_ih, b_hh, out);
}